// Round 1
// baseline (807.519 us; speedup 1.0000x reference)
//
#include <hip/hip_runtime.h>
#include <hip/hip_bf16.h>

// SequenceStateSpace: delta = sigmoid(seq@Wd^T + bd); value = seq@Wv^T + bv;
// out_t = (1-delta_t)*out_{t-1} + delta_t*value_t  (scan over T per (b,d))
//
// Strategy: split-bf16 (hi/lo) MFMA GEMM (3 products -> ~1e-5 rel accuracy),
// fused bias+sigmoid epilogue, then 3-phase chunked parallel scan.

typedef __bf16 bf16;
typedef __bf16 bf16x4 __attribute__((ext_vector_type(4)));
typedef __bf16 bf16x8 __attribute__((ext_vector_type(8)));
typedef float  f32x4  __attribute__((ext_vector_type(4)));

#define NB  8
#define NT  4096
#define ND  1024
#define NM  (NB*NT)      // 32768 rows
#define NN  (2*ND)       // 2048 output cols (delta | value)
#define NK  ND           // 1024

#define CT  128          // scan chunk length
#define NCH (NT/CT)      // 32 chunks per batch

// ---------------- workspace layout (bytes) ----------------
// seq_hi  [NM][NK] bf16 : 67108864
// seq_lo  [NM][NK] bf16 : 67108864
// Bh      [NN][NK] bf16 :  4194304   rows 0..1023 = W_delta, 1024..2047 = W_value
// Bl      [NN][NK] bf16 :  4194304
// value   [NM][ND] f32  : 134217728
// Aarr    [NB*NCH][ND] f32 : 1048576
// Sarr    [NB*NCH][ND] f32 : 1048576
// Sin     [NB*NCH][ND] f32 : 1048576
#define OFF_SEQ_HI 0UL
#define OFF_SEQ_LO 67108864UL
#define OFF_BH     134217728UL
#define OFF_BL     138412032UL
#define OFF_VALUE  142606336UL
#define OFF_AARR   276824064UL
#define OFF_SARR   277872640UL
#define OFF_SIN    278921216UL

#define GLOAD_LDS16(gp, lp)                                                          \
  __builtin_amdgcn_global_load_lds(                                                  \
      (const __attribute__((address_space(1))) void*)(gp),                           \
      (__attribute__((address_space(3))) void*)(lp), 16, 0, 0)

// ---------------- pass 1a: seq -> bf16 hi/lo ----------------
__global__ void k_convert_seq(const float* __restrict__ src,
                              bf16* __restrict__ hi, bf16* __restrict__ lo) {
  const long n4 = (long)NM * NK / 4;
  long i = (long)blockIdx.x * blockDim.x + threadIdx.x;
  const long stride = (long)gridDim.x * blockDim.x;
  const float4* s4 = (const float4*)src;
  bf16x4* h4 = (bf16x4*)hi;
  bf16x4* l4 = (bf16x4*)lo;
  for (; i < n4; i += stride) {
    float4 v = s4[i];
    bf16 h0 = (bf16)v.x, h1 = (bf16)v.y, h2 = (bf16)v.z, h3 = (bf16)v.w;
    bf16 e0 = (bf16)(v.x - (float)h0);
    bf16 e1 = (bf16)(v.y - (float)h1);
    bf16 e2 = (bf16)(v.z - (float)h2);
    bf16 e3 = (bf16)(v.w - (float)h3);
    bf16x4 H; H.x = h0; H.y = h1; H.z = h2; H.w = h3;
    bf16x4 L; L.x = e0; L.y = e1; L.z = e2; L.w = e3;
    h4[i] = H;
    l4[i] = L;
  }
}

// ---------------- pass 1b: W_delta/W_value -> concat bf16 hi/lo ----------------
__global__ void k_convert_w(const float* __restrict__ Wd, const float* __restrict__ Wv,
                            bf16* __restrict__ Bh, bf16* __restrict__ Bl) {
  int tid = blockIdx.x * blockDim.x + threadIdx.x;   // 0..524287
  int n  = tid >> 8;                                  // 0..2047
  int k4 = (tid & 255) * 4;
  const float* src = (n < ND) ? (Wd + (long)n * NK) : (Wv + (long)(n - ND) * NK);
  float4 v = *(const float4*)(src + k4);
  bf16 h0 = (bf16)v.x, h1 = (bf16)v.y, h2 = (bf16)v.z, h3 = (bf16)v.w;
  bf16x4 H; H.x = h0; H.y = h1; H.z = h2; H.w = h3;
  bf16x4 L;
  L.x = (bf16)(v.x - (float)h0);
  L.y = (bf16)(v.y - (float)h1);
  L.z = (bf16)(v.z - (float)h2);
  L.w = (bf16)(v.w - (float)h3);
  *(bf16x4*)(Bh + (long)n * NK + k4) = H;
  *(bf16x4*)(Bl + (long)n * NK + k4) = L;
}

// ---------------- pass 2: GEMM (m97 structure, 128x128 tile, BK=32) ----------------
// out[m][n] = sum_k seq[m][k] * W[n][k]  -> 3-term split-bf16 MFMA
// delta half (n<1024): sigmoid(x+bias) -> d_out;  value half: x+bias -> ws.value
__global__ __launch_bounds__(256) void k_gemm(
    const bf16* __restrict__ Ah_g, const bf16* __restrict__ Al_g,
    const bf16* __restrict__ Bh_g, const bf16* __restrict__ Bl_g,
    const float* __restrict__ bd, const float* __restrict__ bv,
    float* __restrict__ delta_out, float* __restrict__ value_out) {
  __shared__ bf16 Ah[128 * 32], Al[128 * 32], Bh[128 * 32], Bl[128 * 32];

  const int t = threadIdx.x;
  const int w = t >> 6, l = t & 63;
  const int bm = blockIdx.x >> 4, bn = blockIdx.x & 15;  // n fastest: A-panel L2 reuse
  const long m0 = (long)bm * 128;
  const long n0 = (long)bn * 128;
  const int wr = w >> 1, wc = w & 1;           // 2x2 wave grid, 64x64 per wave
  const int lrow = l & 15, lk = l >> 4;        // fragment row / k-octet

  f32x4 acc[4][4] = {};

  const int ck = (t & 3) * 8;                  // staged k-offset (elements)
  const int rA = t >> 2;                       // staged row 0..63 (+64 for j=1)

  for (int k0 = 0; k0 < NK; k0 += 32) {
#pragma unroll
    for (int j = 0; j < 2; ++j) {
      const int r = rA + j * 64;
      const long aoff = (m0 + r) * NK + k0 + ck;
      const long boff = (n0 + r) * NK + k0 + ck;
      const int ldsb = (j * 4 + w) * 512;      // 1KB chunk per wave-instruction
      GLOAD_LDS16(Ah_g + aoff, &Ah[ldsb]);
      GLOAD_LDS16(Al_g + aoff, &Al[ldsb]);
      GLOAD_LDS16(Bh_g + boff, &Bh[ldsb]);
      GLOAD_LDS16(Bl_g + boff, &Bl[ldsb]);
    }
    __syncthreads();

    bf16x8 ah[4], al[4], bh[4], bl[4];
#pragma unroll
    for (int f = 0; f < 4; ++f) {
      const int ao = (wr * 64 + f * 16 + lrow) * 32 + lk * 8;
      const int bo = (wc * 64 + f * 16 + lrow) * 32 + lk * 8;
      ah[f] = *(const bf16x8*)&Ah[ao];
      al[f] = *(const bf16x8*)&Al[ao];
      bh[f] = *(const bf16x8*)&Bh[bo];
      bl[f] = *(const bf16x8*)&Bl[bo];
    }
#pragma unroll
    for (int fm = 0; fm < 4; ++fm)
#pragma unroll
      for (int fn = 0; fn < 4; ++fn) {
        acc[fm][fn] = __builtin_amdgcn_mfma_f32_16x16x32_bf16(ah[fm], bh[fn], acc[fm][fn], 0, 0, 0);
        acc[fm][fn] = __builtin_amdgcn_mfma_f32_16x16x32_bf16(al[fm], bh[fn], acc[fm][fn], 0, 0, 0);
        acc[fm][fn] = __builtin_amdgcn_mfma_f32_16x16x32_bf16(ah[fm], bl[fn], acc[fm][fn], 0, 0, 0);
      }
    __syncthreads();
  }

  const bool isDelta = (n0 < ND);              // block-uniform
#pragma unroll
  for (int fm = 0; fm < 4; ++fm) {
#pragma unroll
    for (int fn = 0; fn < 4; ++fn) {
      const int n = (int)n0 + wc * 64 + fn * 16 + lrow;
      const float bias = isDelta ? bd[n] : bv[n - ND];
#pragma unroll
      for (int r = 0; r < 4; ++r) {
        const long m = m0 + wr * 64 + fm * 16 + lk * 4 + r;
        const float x = acc[fm][fn][r] + bias;
        if (isDelta)
          delta_out[m * ND + n] = 1.0f / (1.0f + __expf(-x));
        else
          value_out[m * ND + (n - ND)] = x;
      }
    }
  }
}

// ---------------- pass 3: chunk-local scan summaries ----------------
// a = prod(1-delta) over chunk; s = chunk response from zero init.
__global__ void k_scan_local(const float* __restrict__ delta, const float* __restrict__ value,
                             float* __restrict__ Aarr, float* __restrict__ Sarr) {
  const int bid = blockIdx.x;                  // 1024 = 8b * 32c * 4dg
  const int dg = bid & 3, c = (bid >> 2) & 31, b = bid >> 7;
  const int d = dg * 256 + threadIdx.x;
  const long base = ((long)b * NT + (long)c * CT) * ND + d;
  float a = 1.0f, s = 0.0f;
#pragma unroll 4
  for (int tt = 0; tt < CT; ++tt) {
    const float dl = delta[base + (long)tt * ND];
    const float v  = value[base + (long)tt * ND];
    const float om = 1.0f - dl;
    a *= om;
    s = om * s + dl * v;
  }
  const int idx = (b * NCH + c) * ND + d;
  Aarr[idx] = a;
  Sarr[idx] = s;
}

// ---------------- pass 4: sequential prefix over chunks (tiny) ----------------
__global__ void k_scan_prefix(const float* __restrict__ Aarr, const float* __restrict__ Sarr,
                              float* __restrict__ Sin) {
  const int tid = blockIdx.x * blockDim.x + threadIdx.x;  // 8192
  const int b = tid >> 10, d = tid & 1023;
  float st = 0.0f;
  for (int c = 0; c < NCH; ++c) {
    const int idx = (b * NCH + c) * ND + d;
    Sin[idx] = st;
    st = Aarr[idx] * st + Sarr[idx];
  }
}

// ---------------- pass 5: apply with true init; overwrite delta with out ----------------
__global__ void k_scan_apply(const float* __restrict__ value, const float* __restrict__ Sin,
                             float* __restrict__ out) {
  const int bid = blockIdx.x;
  const int dg = bid & 3, c = (bid >> 2) & 31, b = bid >> 7;
  const int d = dg * 256 + threadIdx.x;
  const long base = ((long)b * NT + (long)c * CT) * ND + d;
  float st = Sin[(b * NCH + c) * ND + d];
#pragma unroll 4
  for (int tt = 0; tt < CT; ++tt) {
    const long idx = base + (long)tt * ND;
    const float dl = out[idx];                 // delta (in-place, same thread)
    const float v  = value[idx];
    st = (1.0f - dl) * st + dl * v;
    out[idx] = st;
  }
}

extern "C" void kernel_launch(void* const* d_in, const int* in_sizes, int n_in,
                              void* d_out, int out_size, void* d_ws, size_t ws_size,
                              hipStream_t stream) {
  const float* seq = (const float*)d_in[0];
  const float* Wd  = (const float*)d_in[1];
  const float* bd  = (const float*)d_in[2];
  const float* Wv  = (const float*)d_in[3];
  const float* bv  = (const float*)d_in[4];
  float* out = (float*)d_out;

  char* ws = (char*)d_ws;
  bf16*  seq_hi = (bf16*)(ws + OFF_SEQ_HI);
  bf16*  seq_lo = (bf16*)(ws + OFF_SEQ_LO);
  bf16*  Bh     = (bf16*)(ws + OFF_BH);
  bf16*  Bl     = (bf16*)(ws + OFF_BL);
  float* value  = (float*)(ws + OFF_VALUE);
  float* Aarr   = (float*)(ws + OFF_AARR);
  float* Sarr   = (float*)(ws + OFF_SARR);
  float* Sin    = (float*)(ws + OFF_SIN);

  hipLaunchKernelGGL(k_convert_seq, dim3(2048), dim3(256), 0, stream, seq, seq_hi, seq_lo);
  hipLaunchKernelGGL(k_convert_w,   dim3(2048), dim3(256), 0, stream, Wd, Wv, Bh, Bl);
  hipLaunchKernelGGL(k_gemm, dim3(4096), dim3(256), 0, stream,
                     seq_hi, seq_lo, Bh, Bl, bd, bv, out, value);
  hipLaunchKernelGGL(k_scan_local,  dim3(1024), dim3(256), 0, stream, out, value, Aarr, Sarr);
  hipLaunchKernelGGL(k_scan_prefix, dim3(32),   dim3(256), 0, stream, Aarr, Sarr, Sin);
  hipLaunchKernelGGL(k_scan_apply,  dim3(1024), dim3(256), 0, stream, value, Sin, out);
}

// Round 2
// 627.257 us; speedup vs baseline: 1.2874x; 1.2874x over previous
//
#include <hip/hip_runtime.h>
#include <hip/hip_bf16.h>

// SequenceStateSpace: delta = sigmoid(seq@Wd^T + bd); value = seq@Wv^T + bv;
// out_t = (1-delta_t)*out_{t-1} + delta_t*value_t
//
// GEMM: 2-term f16 split as standard K=2048 GEMM (A'=[hi|lo], B'=hi read twice),
// 256x256 tile, BK=64, 8 waves, counted-vmcnt 4-phase schedule, XOR-swizzled LDS.
// Scan: 3-phase chunked parallel scan (unchanged from round 0).

typedef _Float16 f16;
typedef _Float16 f16x8 __attribute__((ext_vector_type(8)));
typedef float    f32x4 __attribute__((ext_vector_type(4)));

#define NB  8
#define NT  4096
#define ND  1024
#define NM  (NB*NT)      // 32768 rows
#define KK  2048         // split-K: [hi | lo]
#define NKT 32           // K-tiles of 64

#define CT  128          // scan chunk length
#define NCH (NT/CT)      // 32 chunks per batch

// ---------------- workspace layout (bytes) ----------------
// Ap [NM][KK]  f16 : 134217728   cols 0..1023 = hi(seq), 1024..2047 = lo(seq)
// Bp [2048][ND] f16:   4194304   rows 0..1023 = hi(Wd), 1024..2047 = hi(Wv)
// value [NM][ND] f32: 134217728
// Aarr/Sarr/Sin [NB*NCH][ND] f32: 1 MiB each
#define OFF_AP     0UL
#define OFF_BP     134217728UL
#define OFF_VALUE  142606336UL
#define OFF_AARR   276824064UL
#define OFF_SARR   277872640UL
#define OFF_SIN    278921216UL

#define GLOAD_LDS16(gp, lp)                                                          \
  __builtin_amdgcn_global_load_lds(                                                  \
      (const __attribute__((address_space(1))) void*)(gp),                           \
      (__attribute__((address_space(3))) void*)(lp), 16, 0, 0)

#define MEMFENCE asm volatile("" ::: "memory")
#define BARRIER() do { MEMFENCE; __builtin_amdgcn_s_barrier(); MEMFENCE; } while (0)
#define WAITV2() asm volatile("s_waitcnt vmcnt(2)" ::: "memory")
#define WAITV0() asm volatile("s_waitcnt vmcnt(0)" ::: "memory")

// ---------------- pass 1a: seq -> f16 hi/lo (K-concat layout) ----------------
__global__ void k_convert_seq(const float* __restrict__ src, f16* __restrict__ Ap) {
  const long n8 = (long)NM * ND / 8;
  long i = (long)blockIdx.x * blockDim.x + threadIdx.x;
  const long stride = (long)gridDim.x * blockDim.x;
  for (; i < n8; i += stride) {
    const long m = i >> 7;
    const int k8 = ((int)i & 127) * 8;
    const float4 v0 = *(const float4*)(src + m * ND + k8);
    const float4 v1 = *(const float4*)(src + m * ND + k8 + 4);
    const float a[8] = {v0.x, v0.y, v0.z, v0.w, v1.x, v1.y, v1.z, v1.w};
    f16x8 hi, lo;
#pragma unroll
    for (int j = 0; j < 8; ++j) {
      const f16 h = (f16)a[j];
      hi[j] = h;
      lo[j] = (f16)(a[j] - (float)h);
    }
    *(f16x8*)(Ap + m * KK + k8) = hi;
    *(f16x8*)(Ap + m * KK + ND + k8) = lo;
  }
}

// ---------------- pass 1b: W_delta/W_value -> f16 hi (concat rows) ----------------
__global__ void k_convert_w(const float* __restrict__ Wd, const float* __restrict__ Wv,
                            f16* __restrict__ Bp) {
  const long i = (long)blockIdx.x * blockDim.x + threadIdx.x;  // 262144 threads
  const int n = (int)(i >> 7);
  const int k8 = ((int)i & 127) * 8;
  const float* row = (n < ND) ? (Wd + (long)n * ND) : (Wv + (long)(n - ND) * ND);
  const float4 v0 = *(const float4*)(row + k8);
  const float4 v1 = *(const float4*)(row + k8 + 4);
  const float a[8] = {v0.x, v0.y, v0.z, v0.w, v1.x, v1.y, v1.z, v1.w};
  f16x8 h;
#pragma unroll
  for (int j = 0; j < 8; ++j) h[j] = (f16)a[j];
  *(f16x8*)(Bp + (long)n * ND + k8) = h;
}

// ---------------- pass 2: GEMM, 256x256 tile, counted-vmcnt 4-phase ----------------
// LDS per buffer: A[256][64] f16 (32KB, XOR-swizzled) + B[256][64] (32KB). 2 buffers.
#define LDS_A(c) ((c) * 65536)
#define LDS_B(c) ((c) * 65536 + 32768)

__global__ __launch_bounds__(512, 2) void k_gemm(
    const f16* __restrict__ Ap, const f16* __restrict__ Bp,
    const float* __restrict__ bd, const float* __restrict__ bv,
    float* __restrict__ dOut, float* __restrict__ vOut) {
  __shared__ char smem[131072];

  const int t = threadIdx.x;
  const int w = t >> 6, lane = t & 63;
  const int wr = w >> 2, wc = w & 3;           // 2(M) x 4(N) waves; wave out = 128x64
  const int l15 = lane & 15, l4 = lane >> 4;

  // XCD-aware bijective swizzle (nwg=1024, %8==0)
  const int bid = blockIdx.x;
  const int sw = (bid & 7) * 128 + (bid >> 3);
  const int bm = sw >> 3, bn = sw & 7;
  const long m0 = (long)bm * 256;
  const int n0 = bn * 256;

  f32x4 acc[8][4] = {};

  // staging constants: half-tile = 128 rows x 64 cols f16 = 16KB; 2 x 16B loads/thread
  const int rl0 = t >> 3;                      // rows 0..63   (q=0)
  const int rl1 = 64 + (t >> 3);               // rows 64..127 (q=1)
  const int c16_0 = (t & 7) ^ (rl0 & 7);       // pre-swizzled source col16
  const int c16_1 = (t & 7) ^ (rl1 & 7);

  auto stageA = [&](int kt, int h, int c) {
    const f16* s0 = Ap + (m0 + h * 128 + rl0) * (long)KK + kt * 64 + c16_0 * 8;
    const f16* s1 = Ap + (m0 + h * 128 + rl1) * (long)KK + kt * 64 + c16_1 * 8;
    char* base = smem + LDS_A(c) + h * 16384 + w * 1024;
    GLOAD_LDS16(s0, base);
    GLOAD_LDS16(s1, base + 8192);
  };
  auto stageB = [&](int kt, int h, int c) {
    const int kb = (kt & 15) * 64;             // B' holds only hi: wrap K
    const f16* s0 = Bp + (long)(n0 + h * 128 + rl0) * ND + kb + c16_0 * 8;
    const f16* s1 = Bp + (long)(n0 + h * 128 + rl1) * ND + kb + c16_1 * 8;
    char* base = smem + LDS_B(c) + h * 16384 + w * 1024;
    GLOAD_LDS16(s0, base);
    GLOAD_LDS16(s1, base + 8192);
  };

  f16x8 aF[8], bF[2];
  auto readA = [&](int c, int k) {
#pragma unroll
    for (int mf = 0; mf < 8; ++mf) {
      const int row = wr * 128 + mf * 16 + l15;
      const int c16 = (k * 4 + l4) ^ (row & 7);
      aF[mf] = *(const f16x8*)(smem + LDS_A(c) + row * 128 + c16 * 16);
    }
  };
  auto readB = [&](int c, int k, int nh) {
#pragma unroll
    for (int nfl = 0; nfl < 2; ++nfl) {
      const int row = nh * 128 + wc * 32 + nfl * 16 + l15;
      const int c16 = (k * 4 + l4) ^ (row & 7);
      bF[nfl] = *(const f16x8*)(smem + LDS_B(c) + row * 128 + c16 * 16);
    }
  };
  auto mfmaQ = [&](int nh) {
    __builtin_amdgcn_s_setprio(1);
#pragma unroll
    for (int mf = 0; mf < 8; ++mf)
#pragma unroll
      for (int nfl = 0; nfl < 2; ++nfl)
        acc[mf][nh * 2 + nfl] = __builtin_amdgcn_mfma_f32_16x16x32_f16(
            aF[mf], bF[nfl], acc[mf][nh * 2 + nfl], 0, 0, 0);
    __builtin_amdgcn_s_setprio(0);
  };

  // One K-tile = 4 phases: (k,nh) = (0,0),(0,1),(1,0),(1,1).
  // Stages trickle next tile's half-tiles (A0,A1,B0,B1) one per phase.
  // vmcnt(2) twice per tile (never 0 until the tail) keeps loads in flight.
  auto tile = [&](int c, int ktNext, bool pf) {
    // phase 0
    if (pf) stageA(ktNext, 0, c ^ 1);
    readA(c, 0); readB(c, 0, 0);
    BARRIER();
    mfmaQ(0);
    if (pf) { WAITV2(); } else { WAITV0(); }   // B1 of current tile landed
    BARRIER();
    // phase 1
    if (pf) stageA(ktNext, 1, c ^ 1);
    readB(c, 0, 1);
    BARRIER();
    mfmaQ(1);
    BARRIER();
    // phase 2
    if (pf) stageB(ktNext, 0, c ^ 1);
    readA(c, 1); readB(c, 1, 0);
    BARRIER();
    mfmaQ(0);
    BARRIER();
    // phase 3
    if (pf) stageB(ktNext, 1, c ^ 1);
    readB(c, 1, 1);
    BARRIER();
    mfmaQ(1);
    if (pf) { WAITV2(); } else { WAITV0(); }   // A0,A1,B0 of next tile landed
    BARRIER();
  };

  // prologue: stage tile 0 into buf0
  stageA(0, 0, 0); stageA(0, 1, 0); stageB(0, 0, 0); stageB(0, 1, 0);
  WAITV2();                                    // A0,A1,B0 of tile 0 landed
  BARRIER();

  for (int i = 0; i < 16; ++i) {
    tile(0, 2 * i + 1, true);
    tile(1, 2 * i + 2, i < 15);
  }

  // epilogue: bias + sigmoid(delta half) / passthrough(value half)
  const bool isDelta = (n0 < ND);              // block-uniform (bn 0-3 delta, 4-7 value)
#pragma unroll
  for (int nf = 0; nf < 4; ++nf) {
    const int sr = (nf >> 1) * 128 + wc * 32 + (nf & 1) * 16 + l15;
    const int n = n0 + sr;
    const float bias = isDelta ? bd[n] : bv[n - ND];
#pragma unroll
    for (int mf = 0; mf < 8; ++mf) {
#pragma unroll
      for (int r = 0; r < 4; ++r) {
        const long m = m0 + wr * 128 + mf * 16 + l4 * 4 + r;
        const float x = acc[mf][nf][r] + bias;
        if (isDelta)
          dOut[m * ND + n] = 1.0f / (1.0f + __expf(-x));
        else
          vOut[m * ND + (n - ND)] = x;
      }
    }
  }
}

// ---------------- pass 3: chunk-local scan summaries ----------------
__global__ void k_scan_local(const float* __restrict__ delta, const float* __restrict__ value,
                             float* __restrict__ Aarr, float* __restrict__ Sarr) {
  const int bid = blockIdx.x;                  // 1024 = 8b * 32c * 4dg
  const int dg = bid & 3, c = (bid >> 2) & 31, b = bid >> 7;
  const int d = dg * 256 + threadIdx.x;
  const long base = ((long)b * NT + (long)c * CT) * ND + d;
  float a = 1.0f, s = 0.0f;
#pragma unroll 4
  for (int tt = 0; tt < CT; ++tt) {
    const float dl = delta[base + (long)tt * ND];
    const float v  = value[base + (long)tt * ND];
    const float om = 1.0f - dl;
    a *= om;
    s = om * s + dl * v;
  }
  const int idx = (b * NCH + c) * ND + d;
  Aarr[idx] = a;
  Sarr[idx] = s;
}

// ---------------- pass 4: sequential prefix over chunks (tiny) ----------------
__global__ void k_scan_prefix(const float* __restrict__ Aarr, const float* __restrict__ Sarr,
                              float* __restrict__ Sin) {
  const int tid = blockIdx.x * blockDim.x + threadIdx.x;  // 8192
  const int b = tid >> 10, d = tid & 1023;
  float st = 0.0f;
  for (int c = 0; c < NCH; ++c) {
    const int idx = (b * NCH + c) * ND + d;
    Sin[idx] = st;
    st = Aarr[idx] * st + Sarr[idx];
  }
}

// ---------------- pass 5: apply with true init; overwrite delta with out ----------------
__global__ void k_scan_apply(const float* __restrict__ value, const float* __restrict__ Sin,
                             float* __restrict__ out) {
  const int bid = blockIdx.x;
  const int dg = bid & 3, c = (bid >> 2) & 31, b = bid >> 7;
  const int d = dg * 256 + threadIdx.x;
  const long base = ((long)b * NT + (long)c * CT) * ND + d;
  float st = Sin[(b * NCH + c) * ND + d];
#pragma unroll 4
  for (int tt = 0; tt < CT; ++tt) {
    const long idx = base + (long)tt * ND;
    const float dl = out[idx];                 // delta (in-place, same thread)
    const float v  = value[idx];
    st = (1.0f - dl) * st + dl * v;
    out[idx] = st;
  }
}

extern "C" void kernel_launch(void* const* d_in, const int* in_sizes, int n_in,
                              void* d_out, int out_size, void* d_ws, size_t ws_size,
                              hipStream_t stream) {
  const float* seq = (const float*)d_in[0];
  const float* Wd  = (const float*)d_in[1];
  const float* bd  = (const float*)d_in[2];
  const float* Wv  = (const float*)d_in[3];
  const float* bv  = (const float*)d_in[4];
  float* out = (float*)d_out;

  char* ws = (char*)d_ws;
  f16*   Ap    = (f16*)(ws + OFF_AP);
  f16*   Bp    = (f16*)(ws + OFF_BP);
  float* value = (float*)(ws + OFF_VALUE);
  float* Aarr  = (float*)(ws + OFF_AARR);
  float* Sarr  = (float*)(ws + OFF_SARR);
  float* Sin   = (float*)(ws + OFF_SIN);

  hipLaunchKernelGGL(k_convert_seq, dim3(2048), dim3(256), 0, stream, seq, Ap);
  hipLaunchKernelGGL(k_convert_w,   dim3(1024), dim3(256), 0, stream, Wd, Wv, Bp);
  hipLaunchKernelGGL(k_gemm, dim3(1024), dim3(512), 0, stream, Ap, Bp, bd, bv, out, value);
  hipLaunchKernelGGL(k_scan_local,  dim3(1024), dim3(256), 0, stream, out, value, Aarr, Sarr);
  hipLaunchKernelGGL(k_scan_prefix, dim3(32),   dim3(256), 0, stream, Aarr, Sarr, Sin);
  hipLaunchKernelGGL(k_scan_apply,  dim3(1024), dim3(256), 0, stream, value, Sin, out);
}

// Round 4
// 624.370 us; speedup vs baseline: 1.2933x; 1.0046x over previous
//
#include <hip/hip_runtime.h>
#include <hip/hip_bf16.h>

// SequenceStateSpace: delta = sigmoid(seq@Wd^T + bd); value = seq@Wv^T + bv;
// out_t = (1-delta_t)*out_{t-1} + delta_t*value_t
//
// GEMM: 2-term f16 split as standard K=2048 GEMM (A'=[hi|lo], B'=hi read twice),
// 256x256 tile, BK=64, 8 waves, counted-vmcnt 4-phase schedule, XOR-swizzled LDS.
// Round 3 (resubmit; prior attempt hit GPU-acquisition timeout):
// swapped MFMA operands (transposed C) -> f32x4 vectorized epilogue stores;
// float4-vectorized scan passes.

typedef _Float16 f16;
typedef _Float16 f16x8 __attribute__((ext_vector_type(8)));
typedef float    f32x4 __attribute__((ext_vector_type(4)));

#define NB  8
#define NT  4096
#define ND  1024
#define NM  (NB*NT)      // 32768 rows
#define KK  2048         // split-K: [hi | lo]

#define CT  128          // scan chunk length
#define NCH (NT/CT)      // 32 chunks per batch

// ---------------- workspace layout (bytes) ----------------
#define OFF_AP     0UL           // Ap [NM][KK] f16
#define OFF_BP     134217728UL   // Bp [2048][ND] f16
#define OFF_VALUE  142606336UL   // value [NM][ND] f32
#define OFF_AARR   276824064UL   // Aarr [NB*NCH][ND] f32
#define OFF_SARR   277872640UL
#define OFF_SIN    278921216UL

#define GLOAD_LDS16(gp, lp)                                                          \
  __builtin_amdgcn_global_load_lds(                                                  \
      (const __attribute__((address_space(1))) void*)(gp),                           \
      (__attribute__((address_space(3))) void*)(lp), 16, 0, 0)

#define MEMFENCE asm volatile("" ::: "memory")
#define BARRIER() do { MEMFENCE; __builtin_amdgcn_s_barrier(); MEMFENCE; } while (0)
#define WAITV2() asm volatile("s_waitcnt vmcnt(2)" ::: "memory")
#define WAITV0() asm volatile("s_waitcnt vmcnt(0)" ::: "memory")

// ---------------- pass 1a: seq -> f16 hi/lo (K-concat layout) ----------------
__global__ void k_convert_seq(const float* __restrict__ src, f16* __restrict__ Ap) {
  const long n8 = (long)NM * ND / 8;
  long i = (long)blockIdx.x * blockDim.x + threadIdx.x;
  const long stride = (long)gridDim.x * blockDim.x;
  for (; i < n8; i += stride) {
    const long m = i >> 7;
    const int k8 = ((int)i & 127) * 8;
    const float4 v0 = *(const float4*)(src + m * ND + k8);
    const float4 v1 = *(const float4*)(src + m * ND + k8 + 4);
    const float a[8] = {v0.x, v0.y, v0.z, v0.w, v1.x, v1.y, v1.z, v1.w};
    f16x8 hi, lo;
#pragma unroll
    for (int j = 0; j < 8; ++j) {
      const f16 h = (f16)a[j];
      hi[j] = h;
      lo[j] = (f16)(a[j] - (float)h);
    }
    *(f16x8*)(Ap + m * KK + k8) = hi;
    *(f16x8*)(Ap + m * KK + ND + k8) = lo;
  }
}

// ---------------- pass 1b: W_delta/W_value -> f16 hi (concat rows) ----------------
__global__ void k_convert_w(const float* __restrict__ Wd, const float* __restrict__ Wv,
                            f16* __restrict__ Bp) {
  const long i = (long)blockIdx.x * blockDim.x + threadIdx.x;  // 262144 threads
  const int n = (int)(i >> 7);
  const int k8 = ((int)i & 127) * 8;
  const float* row = (n < ND) ? (Wd + (long)n * ND) : (Wv + (long)(n - ND) * ND);
  const float4 v0 = *(const float4*)(row + k8);
  const float4 v1 = *(const float4*)(row + k8 + 4);
  const float a[8] = {v0.x, v0.y, v0.z, v0.w, v1.x, v1.y, v1.z, v1.w};
  f16x8 h;
#pragma unroll
  for (int j = 0; j < 8; ++j) h[j] = (f16)a[j];
  *(f16x8*)(Bp + (long)n * ND + k8) = h;
}

// ---------------- pass 2: GEMM, 256x256 tile, counted-vmcnt 4-phase ----------------
#define LDS_A(c) ((c) * 65536)
#define LDS_B(c) ((c) * 65536 + 32768)

__global__ __launch_bounds__(512, 2) void k_gemm(
    const f16* __restrict__ Ap, const f16* __restrict__ Bp,
    const float* __restrict__ bd, const float* __restrict__ bv,
    float* __restrict__ dOut, float* __restrict__ vOut) {
  __shared__ char smem[131072];

  const int t = threadIdx.x;
  const int w = t >> 6, lane = t & 63;
  const int wr = w >> 2, wc = w & 3;           // 2(M) x 4(N) waves; wave out = 128x64
  const int l15 = lane & 15, l4 = lane >> 4;

  // XCD-aware bijective swizzle (nwg=1024, %8==0)
  const int bid = blockIdx.x;
  const int sw = (bid & 7) * 128 + (bid >> 3);
  const int bm = sw >> 3, bn = sw & 7;
  const long m0 = (long)bm * 256;
  const int n0 = bn * 256;

  f32x4 acc[8][4] = {};

  // staging: half-tile = 128 rows x 64 cols f16 = 16KB; 2 x 16B loads/thread
  const int rl0 = t >> 3;                      // rows 0..63
  const int rl1 = 64 + (t >> 3);               // rows 64..127
  const int c16_0 = (t & 7) ^ (rl0 & 7);       // pre-swizzled source col16
  const int c16_1 = (t & 7) ^ (rl1 & 7);

  auto stageA = [&](int kt, int h, int c) {
    const f16* s0 = Ap + (m0 + h * 128 + rl0) * (long)KK + kt * 64 + c16_0 * 8;
    const f16* s1 = Ap + (m0 + h * 128 + rl1) * (long)KK + kt * 64 + c16_1 * 8;
    char* base = smem + LDS_A(c) + h * 16384 + w * 1024;
    GLOAD_LDS16(s0, base);
    GLOAD_LDS16(s1, base + 8192);
  };
  auto stageB = [&](int kt, int h, int c) {
    const int kb = (kt & 15) * 64;             // B' holds only hi: wrap K
    const f16* s0 = Bp + (long)(n0 + h * 128 + rl0) * ND + kb + c16_0 * 8;
    const f16* s1 = Bp + (long)(n0 + h * 128 + rl1) * ND + kb + c16_1 * 8;
    char* base = smem + LDS_B(c) + h * 16384 + w * 1024;
    GLOAD_LDS16(s0, base);
    GLOAD_LDS16(s1, base + 8192);
  };

  f16x8 aF[8], bF[2];
  auto readA = [&](int c, int k) {
#pragma unroll
    for (int mf = 0; mf < 8; ++mf) {
      const int row = wr * 128 + mf * 16 + l15;
      const int c16 = (k * 4 + l4) ^ (row & 7);
      aF[mf] = *(const f16x8*)(smem + LDS_A(c) + row * 128 + c16 * 16);
    }
  };
  auto readB = [&](int c, int k, int nh) {
#pragma unroll
    for (int nfl = 0; nfl < 2; ++nfl) {
      const int row = nh * 128 + wc * 32 + nfl * 16 + l15;
      const int c16 = (k * 4 + l4) ^ (row & 7);
      bF[nfl] = *(const f16x8*)(smem + LDS_B(c) + row * 128 + c16 * 16);
    }
  };
  // Swapped operands: D = transpose -> lane l15 holds m, (l4*4+r) holds n.
  auto mfmaQ = [&](int nh) {
    __builtin_amdgcn_s_setprio(1);
#pragma unroll
    for (int mf = 0; mf < 8; ++mf)
#pragma unroll
      for (int nfl = 0; nfl < 2; ++nfl)
        acc[mf][nh * 2 + nfl] = __builtin_amdgcn_mfma_f32_16x16x32_f16(
            bF[nfl], aF[mf], acc[mf][nh * 2 + nfl], 0, 0, 0);
    __builtin_amdgcn_s_setprio(0);
  };

  auto tile = [&](int c, int ktNext, bool pf) {
    // phase 0
    if (pf) stageA(ktNext, 0, c ^ 1);
    readA(c, 0); readB(c, 0, 0);
    BARRIER();
    mfmaQ(0);
    if (pf) { WAITV2(); } else { WAITV0(); }   // B1 of current tile landed
    BARRIER();
    // phase 1
    if (pf) stageA(ktNext, 1, c ^ 1);
    readB(c, 0, 1);
    BARRIER();
    mfmaQ(1);
    BARRIER();
    // phase 2
    if (pf) stageB(ktNext, 0, c ^ 1);
    readA(c, 1); readB(c, 1, 0);
    BARRIER();
    mfmaQ(0);
    BARRIER();
    // phase 3
    if (pf) stageB(ktNext, 1, c ^ 1);
    readB(c, 1, 1);
    BARRIER();
    mfmaQ(1);
    if (pf) { WAITV2(); } else { WAITV0(); }   // A0,A1,B0 of next tile landed
    BARRIER();
  };

  // prologue: stage tile 0 into buf0
  stageA(0, 0, 0); stageA(0, 1, 0); stageB(0, 0, 0); stageB(0, 1, 0);
  WAITV2();
  BARRIER();

  for (int i = 0; i < 16; ++i) {
    tile(0, 2 * i + 1, true);
    tile(1, 2 * i + 2, i < 15);
  }

  // epilogue: vectorized f32x4 stores along n
  const bool isDelta = (n0 < ND);              // block-uniform
#pragma unroll
  for (int nf = 0; nf < 4; ++nf) {
    const int nb = n0 + (nf >> 1) * 128 + wc * 32 + (nf & 1) * 16 + l4 * 4;
    const float4 bias = *(const float4*)(isDelta ? (bd + nb) : (bv + (nb - ND)));
#pragma unroll
    for (int mf = 0; mf < 8; ++mf) {
      const long m = m0 + wr * 128 + mf * 16 + l15;
      f32x4 x = acc[mf][nf];
      x[0] += bias.x; x[1] += bias.y; x[2] += bias.z; x[3] += bias.w;
      if (isDelta) {
#pragma unroll
        for (int r = 0; r < 4; ++r) x[r] = 1.0f / (1.0f + __expf(-x[r]));
        *(f32x4*)(dOut + m * ND + nb) = x;
      } else {
        *(f32x4*)(vOut + m * ND + (nb - ND)) = x;
      }
    }
  }
}

// ---------------- pass 3: chunk-local scan summaries (float4 per thread) ----------------
__global__ void k_scan_local(const float* __restrict__ delta, const float* __restrict__ value,
                             float* __restrict__ Aarr, float* __restrict__ Sarr) {
  const int bid = blockIdx.x;                  // 256 = 8b * 32c
  const int c = bid & 31, b = bid >> 5;
  const int d = threadIdx.x * 4;
  const long base = ((long)b * NT + (long)c * CT) * ND + d;
  float4 a = make_float4(1.f, 1.f, 1.f, 1.f);
  float4 s = make_float4(0.f, 0.f, 0.f, 0.f);
#pragma unroll 4
  for (int tt = 0; tt < CT; ++tt) {
    const float4 dl = *(const float4*)(delta + base + (long)tt * ND);
    const float4 v  = *(const float4*)(value + base + (long)tt * ND);
    const float o0 = 1.0f - dl.x, o1 = 1.0f - dl.y, o2 = 1.0f - dl.z, o3 = 1.0f - dl.w;
    a.x *= o0; a.y *= o1; a.z *= o2; a.w *= o3;
    s.x = o0 * s.x + dl.x * v.x;
    s.y = o1 * s.y + dl.y * v.y;
    s.z = o2 * s.z + dl.z * v.z;
    s.w = o3 * s.w + dl.w * v.w;
  }
  const long o = (long)(b * NCH + c) * ND + d;
  *(float4*)(Aarr + o) = a;
  *(float4*)(Sarr + o) = s;
}

// ---------------- pass 4: sequential prefix over chunks (tiny) ----------------
__global__ void k_scan_prefix(const float* __restrict__ Aarr, const float* __restrict__ Sarr,
                              float* __restrict__ Sin) {
  const int tid = blockIdx.x * blockDim.x + threadIdx.x;  // 2048
  const int b = tid >> 8, d = (tid & 255) * 4;
  float4 st = make_float4(0.f, 0.f, 0.f, 0.f);
  for (int c = 0; c < NCH; ++c) {
    const long idx = (long)(b * NCH + c) * ND + d;
    *(float4*)(Sin + idx) = st;
    const float4 a = *(const float4*)(Aarr + idx);
    const float4 s = *(const float4*)(Sarr + idx);
    st.x = a.x * st.x + s.x;
    st.y = a.y * st.y + s.y;
    st.z = a.z * st.z + s.z;
    st.w = a.w * st.w + s.w;
  }
}

// ---------------- pass 5: apply with true init; overwrite delta with out ----------------
__global__ void k_scan_apply(const float* __restrict__ value, const float* __restrict__ Sin,
                             float* __restrict__ out) {
  const int bid = blockIdx.x;                  // 256 = 8b * 32c
  const int c = bid & 31, b = bid >> 5;
  const int d = threadIdx.x * 4;
  const long base = ((long)b * NT + (long)c * CT) * ND + d;
  float4 st = *(const float4*)(Sin + (long)(b * NCH + c) * ND + d);
#pragma unroll 4
  for (int tt = 0; tt < CT; ++tt) {
    const long idx = base + (long)tt * ND;
    const float4 dl = *(const float4*)(out + idx);     // delta (in-place)
    const float4 v  = *(const float4*)(value + idx);
    st.x = (1.0f - dl.x) * st.x + dl.x * v.x;
    st.y = (1.0f - dl.y) * st.y + dl.y * v.y;
    st.z = (1.0f - dl.z) * st.z + dl.z * v.z;
    st.w = (1.0f - dl.w) * st.w + dl.w * v.w;
    *(float4*)(out + idx) = st;
  }
}

extern "C" void kernel_launch(void* const* d_in, const int* in_sizes, int n_in,
                              void* d_out, int out_size, void* d_ws, size_t ws_size,
                              hipStream_t stream) {
  const float* seq = (const float*)d_in[0];
  const float* Wd  = (const float*)d_in[1];
  const float* bd  = (const float*)d_in[2];
  const float* Wv  = (const float*)d_in[3];
  const float* bv  = (const float*)d_in[4];
  float* out = (float*)d_out;

  char* ws = (char*)d_ws;
  f16*   Ap    = (f16*)(ws + OFF_AP);
  f16*   Bp    = (f16*)(ws + OFF_BP);
  float* value = (float*)(ws + OFF_VALUE);
  float* Aarr  = (float*)(ws + OFF_AARR);
  float* Sarr  = (float*)(ws + OFF_SARR);
  float* Sin   = (float*)(ws + OFF_SIN);

  hipLaunchKernelGGL(k_convert_seq, dim3(2048), dim3(256), 0, stream, seq, Ap);
  hipLaunchKernelGGL(k_convert_w,   dim3(1024), dim3(256), 0, stream, Wd, Wv, Bp);
  hipLaunchKernelGGL(k_gemm, dim3(1024), dim3(512), 0, stream, Ap, Bp, bd, bv, out, value);
  hipLaunchKernelGGL(k_scan_local,  dim3(256), dim3(256), 0, stream, out, value, Aarr, Sarr);
  hipLaunchKernelGGL(k_scan_prefix, dim3(8),   dim3(256), 0, stream, Aarr, Sarr, Sin);
  hipLaunchKernelGGL(k_scan_apply,  dim3(256), dim3(256), 0, stream, value, Sin, out);
}

// Round 5
// 519.108 us; speedup vs baseline: 1.5556x; 1.2028x over previous
//
#include <hip/hip_runtime.h>
#include <hip/hip_bf16.h>

// SequenceStateSpace: delta = sigmoid(seq@Wd^T + bd); value = seq@Wv^T + bv;
// out_t = (1-delta_t)*out_{t-1} + delta_t*value_t
//
// Round 5: pure-f16 GEMM (K=1024, no lo-term; absmax floor at 2^-7 is
// GEMM-invisible per rounds 1/2/4), scan chunk CT=64 (512 blocks, 2/CU).
// GEMM: 256x256 tile, BK=64, 8 waves, counted-vmcnt 4-phase schedule,
// XOR-swizzled LDS, swapped-operand MFMA -> f32x4 epilogue.

typedef _Float16 f16;
typedef _Float16 f16x8 __attribute__((ext_vector_type(8)));
typedef float    f32x4 __attribute__((ext_vector_type(4)));

#define NB  8
#define NT  4096
#define ND  1024
#define NM  (NB*NT)      // 32768 rows
#define KK  1024         // f16-hi only

#define CT  64           // scan chunk length
#define NCH (NT/CT)      // 64 chunks per batch

// ---------------- workspace layout (bytes) ----------------
#define OFF_AP     0UL           // Ap [NM][KK] f16      : 67108864
#define OFF_BP     67108864UL    // Bp [2048][ND] f16    :  4194304
#define OFF_VALUE  71303168UL    // value [NM][ND] f32   : 134217728
#define OFF_AARR   205520896UL   // Aarr [NB*NCH][ND] f32:   2097152
#define OFF_SARR   207618048UL
#define OFF_SIN    209715200UL

#define GLOAD_LDS16(gp, lp)                                                          \
  __builtin_amdgcn_global_load_lds(                                                  \
      (const __attribute__((address_space(1))) void*)(gp),                           \
      (__attribute__((address_space(3))) void*)(lp), 16, 0, 0)

#define MEMFENCE asm volatile("" ::: "memory")
#define BARRIER() do { MEMFENCE; __builtin_amdgcn_s_barrier(); MEMFENCE; } while (0)
#define WAITV2() asm volatile("s_waitcnt vmcnt(2)" ::: "memory")
#define WAITV0() asm volatile("s_waitcnt vmcnt(0)" ::: "memory")

// ---------------- pass 1a: seq -> f16 (round to hi) ----------------
__global__ void k_convert_seq(const float* __restrict__ src, f16* __restrict__ Ap) {
  const long n8 = (long)NM * ND / 8;
  long i = (long)blockIdx.x * blockDim.x + threadIdx.x;
  const long stride = (long)gridDim.x * blockDim.x;
  for (; i < n8; i += stride) {
    const float4 v0 = *(const float4*)(src + i * 8);
    const float4 v1 = *(const float4*)(src + i * 8 + 4);
    f16x8 h;
    h[0] = (f16)v0.x; h[1] = (f16)v0.y; h[2] = (f16)v0.z; h[3] = (f16)v0.w;
    h[4] = (f16)v1.x; h[5] = (f16)v1.y; h[6] = (f16)v1.z; h[7] = (f16)v1.w;
    *((f16x8*)Ap + i) = h;
  }
}

// ---------------- pass 1b: W_delta/W_value -> f16 (concat rows) ----------------
__global__ void k_convert_w(const float* __restrict__ Wd, const float* __restrict__ Wv,
                            f16* __restrict__ Bp) {
  const long i = (long)blockIdx.x * blockDim.x + threadIdx.x;  // 262144 threads
  const int n = (int)(i >> 7);
  const int k8 = ((int)i & 127) * 8;
  const float* row = (n < ND) ? (Wd + (long)n * ND) : (Wv + (long)(n - ND) * ND);
  const float4 v0 = *(const float4*)(row + k8);
  const float4 v1 = *(const float4*)(row + k8 + 4);
  f16x8 h;
  h[0] = (f16)v0.x; h[1] = (f16)v0.y; h[2] = (f16)v0.z; h[3] = (f16)v0.w;
  h[4] = (f16)v1.x; h[5] = (f16)v1.y; h[6] = (f16)v1.z; h[7] = (f16)v1.w;
  *(f16x8*)(Bp + (long)n * ND + k8) = h;
}

// ---------------- pass 2: GEMM, 256x256 tile, counted-vmcnt 4-phase ----------------
#define LDS_A(c) ((c) * 65536)
#define LDS_B(c) ((c) * 65536 + 32768)

__global__ __launch_bounds__(512, 2) void k_gemm(
    const f16* __restrict__ Ap, const f16* __restrict__ Bp,
    const float* __restrict__ bd, const float* __restrict__ bv,
    float* __restrict__ dOut, float* __restrict__ vOut) {
  __shared__ char smem[131072];

  const int t = threadIdx.x;
  const int w = t >> 6, lane = t & 63;
  const int wr = w >> 2, wc = w & 3;           // 2(M) x 4(N) waves; wave out = 128x64
  const int l15 = lane & 15, l4 = lane >> 4;

  // XCD-aware bijective swizzle (nwg=1024, %8==0)
  const int bid = blockIdx.x;
  const int sw = (bid & 7) * 128 + (bid >> 3);
  const int bm = sw >> 3, bn = sw & 7;
  const long m0 = (long)bm * 256;
  const int n0 = bn * 256;

  f32x4 acc[8][4] = {};

  // staging: half-tile = 128 rows x 64 cols f16 = 16KB; 2 x 16B loads/thread
  const int rl0 = t >> 3;                      // rows 0..63
  const int rl1 = 64 + (t >> 3);               // rows 64..127
  const int c16_0 = (t & 7) ^ (rl0 & 7);       // pre-swizzled source col16
  const int c16_1 = (t & 7) ^ (rl1 & 7);

  auto stageA = [&](int kt, int h, int c) {
    const f16* s0 = Ap + (m0 + h * 128 + rl0) * (long)KK + kt * 64 + c16_0 * 8;
    const f16* s1 = Ap + (m0 + h * 128 + rl1) * (long)KK + kt * 64 + c16_1 * 8;
    char* base = smem + LDS_A(c) + h * 16384 + w * 1024;
    GLOAD_LDS16(s0, base);
    GLOAD_LDS16(s1, base + 8192);
  };
  auto stageB = [&](int kt, int h, int c) {
    const f16* s0 = Bp + (long)(n0 + h * 128 + rl0) * ND + kt * 64 + c16_0 * 8;
    const f16* s1 = Bp + (long)(n0 + h * 128 + rl1) * ND + kt * 64 + c16_1 * 8;
    char* base = smem + LDS_B(c) + h * 16384 + w * 1024;
    GLOAD_LDS16(s0, base);
    GLOAD_LDS16(s1, base + 8192);
  };

  f16x8 aF[8], bF[2];
  auto readA = [&](int c, int k) {
#pragma unroll
    for (int mf = 0; mf < 8; ++mf) {
      const int row = wr * 128 + mf * 16 + l15;
      const int c16 = (k * 4 + l4) ^ (row & 7);
      aF[mf] = *(const f16x8*)(smem + LDS_A(c) + row * 128 + c16 * 16);
    }
  };
  auto readB = [&](int c, int k, int nh) {
#pragma unroll
    for (int nfl = 0; nfl < 2; ++nfl) {
      const int row = nh * 128 + wc * 32 + nfl * 16 + l15;
      const int c16 = (k * 4 + l4) ^ (row & 7);
      bF[nfl] = *(const f16x8*)(smem + LDS_B(c) + row * 128 + c16 * 16);
    }
  };
  // Swapped operands: D = transpose -> lane l15 holds m, (l4*4+r) holds n.
  auto mfmaQ = [&](int nh) {
    __builtin_amdgcn_s_setprio(1);
#pragma unroll
    for (int mf = 0; mf < 8; ++mf)
#pragma unroll
      for (int nfl = 0; nfl < 2; ++nfl)
        acc[mf][nh * 2 + nfl] = __builtin_amdgcn_mfma_f32_16x16x32_f16(
            bF[nfl], aF[mf], acc[mf][nh * 2 + nfl], 0, 0, 0);
    __builtin_amdgcn_s_setprio(0);
  };

  auto tile = [&](int c, int ktNext, bool pf) {
    // phase 0 (needs A0,A1,B0 of current tile: guaranteed by prior vmcnt(2))
    if (pf) stageA(ktNext, 0, c ^ 1);
    readA(c, 0); readB(c, 0, 0);
    BARRIER();
    mfmaQ(0);
    if (pf) { WAITV2(); } else { WAITV0(); }   // B1 of current tile landed
    BARRIER();
    // phase 1
    if (pf) stageA(ktNext, 1, c ^ 1);
    readB(c, 0, 1);
    BARRIER();
    mfmaQ(1);
    BARRIER();
    // phase 2
    if (pf) stageB(ktNext, 0, c ^ 1);
    readA(c, 1); readB(c, 1, 0);
    BARRIER();
    mfmaQ(0);
    BARRIER();
    // phase 3
    if (pf) stageB(ktNext, 1, c ^ 1);
    readB(c, 1, 1);
    BARRIER();
    mfmaQ(1);
    if (pf) { WAITV2(); } else { WAITV0(); }   // A0,A1,B0 of next tile landed
    BARRIER();
  };

  // prologue: stage tile 0 into buf0
  stageA(0, 0, 0); stageA(0, 1, 0); stageB(0, 0, 0); stageB(0, 1, 0);
  WAITV2();
  BARRIER();

  for (int i = 0; i < 8; ++i) {               // 16 K-tiles of 64 (K=1024)
    tile(0, 2 * i + 1, true);
    tile(1, 2 * i + 2, i < 7);
  }

  // epilogue: vectorized f32x4 stores along n
  const bool isDelta = (n0 < ND);              // block-uniform
#pragma unroll
  for (int nf = 0; nf < 4; ++nf) {
    const int nb = n0 + (nf >> 1) * 128 + wc * 32 + (nf & 1) * 16 + l4 * 4;
    const float4 bias = *(const float4*)(isDelta ? (bd + nb) : (bv + (nb - ND)));
#pragma unroll
    for (int mf = 0; mf < 8; ++mf) {
      const long m = m0 + wr * 128 + mf * 16 + l15;
      f32x4 x = acc[mf][nf];
      x[0] += bias.x; x[1] += bias.y; x[2] += bias.z; x[3] += bias.w;
      if (isDelta) {
#pragma unroll
        for (int r = 0; r < 4; ++r) x[r] = 1.0f / (1.0f + __expf(-x[r]));
        *(f32x4*)(dOut + m * ND + nb) = x;
      } else {
        *(f32x4*)(vOut + m * ND + (nb - ND)) = x;
      }
    }
  }
}

// ---------------- pass 3: chunk-local scan summaries (float4 per thread) ----------------
__global__ void k_scan_local(const float* __restrict__ delta, const float* __restrict__ value,
                             float* __restrict__ Aarr, float* __restrict__ Sarr) {
  const int bid = blockIdx.x;                  // 512 = 8b * 64c
  const int c = bid & 63, b = bid >> 6;
  const int d = threadIdx.x * 4;
  const long base = ((long)b * NT + (long)c * CT) * ND + d;
  float4 a = make_float4(1.f, 1.f, 1.f, 1.f);
  float4 s = make_float4(0.f, 0.f, 0.f, 0.f);
#pragma unroll 4
  for (int tt = 0; tt < CT; ++tt) {
    const float4 dl = *(const float4*)(delta + base + (long)tt * ND);
    const float4 v  = *(const float4*)(value + base + (long)tt * ND);
    const float o0 = 1.0f - dl.x, o1 = 1.0f - dl.y, o2 = 1.0f - dl.z, o3 = 1.0f - dl.w;
    a.x *= o0; a.y *= o1; a.z *= o2; a.w *= o3;
    s.x = o0 * s.x + dl.x * v.x;
    s.y = o1 * s.y + dl.y * v.y;
    s.z = o2 * s.z + dl.z * v.z;
    s.w = o3 * s.w + dl.w * v.w;
  }
  const long o = (long)(b * NCH + c) * ND + d;
  *(float4*)(Aarr + o) = a;
  *(float4*)(Sarr + o) = s;
}

// ---------------- pass 4: sequential prefix over chunks (tiny) ----------------
__global__ void k_scan_prefix(const float* __restrict__ Aarr, const float* __restrict__ Sarr,
                              float* __restrict__ Sin) {
  const int tid = blockIdx.x * blockDim.x + threadIdx.x;  // 2048
  const int b = tid >> 8, d = (tid & 255) * 4;
  float4 st = make_float4(0.f, 0.f, 0.f, 0.f);
  for (int c = 0; c < NCH; ++c) {
    const long idx = (long)(b * NCH + c) * ND + d;
    *(float4*)(Sin + idx) = st;
    const float4 a = *(const float4*)(Aarr + idx);
    const float4 s = *(const float4*)(Sarr + idx);
    st.x = a.x * st.x + s.x;
    st.y = a.y * st.y + s.y;
    st.z = a.z * st.z + s.z;
    st.w = a.w * st.w + s.w;
  }
}

// ---------------- pass 5: apply with true init; overwrite delta with out ----------------
__global__ void k_scan_apply(const float* __restrict__ value, const float* __restrict__ Sin,
                             float* __restrict__ out) {
  const int bid = blockIdx.x;                  // 512 = 8b * 64c
  const int c = bid & 63, b = bid >> 6;
  const int d = threadIdx.x * 4;
  const long base = ((long)b * NT + (long)c * CT) * ND + d;
  float4 st = *(const float4*)(Sin + (long)(b * NCH + c) * ND + d);
#pragma unroll 4
  for (int tt = 0; tt < CT; ++tt) {
    const long idx = base + (long)tt * ND;
    const float4 dl = *(const float4*)(out + idx);     // delta (in-place)
    const float4 v  = *(const float4*)(value + idx);
    st.x = (1.0f - dl.x) * st.x + dl.x * v.x;
    st.y = (1.0f - dl.y) * st.y + dl.y * v.y;
    st.z = (1.0f - dl.z) * st.z + dl.z * v.z;
    st.w = (1.0f - dl.w) * st.w + dl.w * v.w;
    *(float4*)(out + idx) = st;
  }
}

extern "C" void kernel_launch(void* const* d_in, const int* in_sizes, int n_in,
                              void* d_out, int out_size, void* d_ws, size_t ws_size,
                              hipStream_t stream) {
  const float* seq = (const float*)d_in[0];
  const float* Wd  = (const float*)d_in[1];
  const float* bd  = (const float*)d_in[2];
  const float* Wv  = (const float*)d_in[3];
  const float* bv  = (const float*)d_in[4];
  float* out = (float*)d_out;

  char* ws = (char*)d_ws;
  f16*   Ap    = (f16*)(ws + OFF_AP);
  f16*   Bp    = (f16*)(ws + OFF_BP);
  float* value = (float*)(ws + OFF_VALUE);
  float* Aarr  = (float*)(ws + OFF_AARR);
  float* Sarr  = (float*)(ws + OFF_SARR);
  float* Sin   = (float*)(ws + OFF_SIN);

  hipLaunchKernelGGL(k_convert_seq, dim3(2048), dim3(256), 0, stream, seq, Ap);
  hipLaunchKernelGGL(k_convert_w,   dim3(1024), dim3(256), 0, stream, Wd, Wv, Bp);
  hipLaunchKernelGGL(k_gemm, dim3(1024), dim3(512), 0, stream, Ap, Bp, bd, bv, out, value);
  hipLaunchKernelGGL(k_scan_local,  dim3(512), dim3(256), 0, stream, out, value, Aarr, Sarr);
  hipLaunchKernelGGL(k_scan_prefix, dim3(8),   dim3(256), 0, stream, Aarr, Sarr, Sin);
  hipLaunchKernelGGL(k_scan_apply,  dim3(512), dim3(256), 0, stream, value, Sin, out);
}